// Round 9
// baseline (309.422 us; speedup 1.0000x reference)
//
#include <hip/hip_runtime.h>

#define NDOCS 64
#define NPASS 1024
#define TITLE_LEN 128
#define SEQ 256
#define NEDGES 32768
#define NNODES 2112   // NDOCS + 2*NPASS
#define DIM 768
#define SPAN_TOK 30522
#define NREL 2
#define NBINS (NREL * NNODES)   // 4224
#define SPAN0 (NNODES - NPASS)  // 1088
#define NBLK 528                // 528 blocks * 4 waves = 2112 waves
#define NSYNC 5
// clear region: accP (NNODES*6) | zacc (NPASS*2) | deg (NBINS) | bars (2*NSYNC)
#define CLRWORDS (NNODES * 6 + NPASS * 2 + NBINS + 2 * NSYNC)

__device__ inline float wred(float s) {
#pragma unroll
  for (int off = 32; off > 0; off >>= 1) s += __shfl_down(s, off);
  return s;
}
__device__ inline float dot4(float4 a, float4 b) {
  return a.x * b.x + a.y * b.y + a.z * b.z + a.w * b.w;
}

// grid-wide barrier: per-sync {flag, cnt} zeroed by init_kernel each launch
__device__ inline void gbar(int* bars, int i) {
  __syncthreads();
  if (threadIdx.x == 0) {
    __threadfence();
    int* cnt = &bars[2 * i];
    int* flag = &bars[2 * i + 1];
    if (__hip_atomic_fetch_add(cnt, 1, __ATOMIC_ACQ_REL,
                               __HIP_MEMORY_SCOPE_AGENT) == NBLK - 1) {
      __hip_atomic_store(flag, 1, __ATOMIC_RELEASE, __HIP_MEMORY_SCOPE_AGENT);
    } else {
      while (__hip_atomic_load(flag, __ATOMIC_ACQUIRE,
                               __HIP_MEMORY_SCOPE_AGENT) == 0)
        __builtin_amdgcn_s_sleep(1);
    }
  }
  __syncthreads();
}

__global__ __launch_bounds__(256) void init_kernel(int* __restrict__ clr) {
  int i = blockIdx.x * 256 + threadIdx.x;
  if (i < CLRWORDS) clr[i] = 0;
}

__global__ __launch_bounds__(256) void mega_kernel(
    const int* __restrict__ doc_ids, const int* __restrict__ pass_ids,
    const int* __restrict__ src, const int* __restrict__ dst,
    const int* __restrict__ et, const float* __restrict__ embed,
    const float* __restrict__ w_root1, const float* __restrict__ w_rel1,
    const float* __restrict__ b1, const float* __restrict__ w_root2,
    const float* __restrict__ w_rel2, const float* __restrict__ b2,
    const float* __restrict__ clf_w, const float* __restrict__ clf_b,
    float4* __restrict__ U4, float4* __restrict__ Tq, float* __restrict__ v,
    float* __restrict__ accP, float* __restrict__ zacc, int* __restrict__ deg,
    int* __restrict__ bars, float* __restrict__ out) {
  const int w = blockIdx.x * 4 + (threadIdx.x >> 6);  // global wave id 0..2111
  const int lane = threadIdx.x & 63;
  const int gtid = blockIdx.x * 256 + threadIdx.x;

  // ---- stage A: foldv (v = Wcat2 . clf_w) || hist ----
  for (int k = w; k <= 3 * DIM; k += 4 * NBLK) {
    const float* row = (k < DIM) ? w_root2 + (size_t)k * DIM
                     : (k < 3 * DIM) ? w_rel2 + (size_t)(k - DIM) * DIM
                                     : b2;
    const float4* r4 = (const float4*)row;
    const float4* w4 = (const float4*)clf_w;
    float s = 0.f;
#pragma unroll
    for (int i = 0; i < 3; ++i) {
      int j = lane + i * 64;
      s += dot4(r4[j], w4[j]);
    }
    s = wred(s);
    if (lane == 0) v[k] = s + (k == 3 * DIM ? clf_b[0] : 0.f);
  }
  if (gtid < NEDGES) atomicAdd(&deg[et[gtid] * NNODES + dst[gtid]], 1);
  gbar(bars, 0);

  // ---- stage B: foldu (U4[k] = {row_k(Wcat1).v0,.v1,.v2}; U4[2304]=d) ----
  for (int k = w; k <= 3 * DIM; k += 4 * NBLK) {
    const float* row = (k < DIM) ? w_root1 + (size_t)k * DIM
                     : (k < 3 * DIM) ? w_rel1 + (size_t)(k - DIM) * DIM
                                     : b1;
    const float4* r4 = (const float4*)row;
    const float4* v0 = (const float4*)v;
    const float4* v1 = (const float4*)(v + DIM);
    const float4* v2 = (const float4*)(v + 2 * DIM);
    float s0 = 0.f, s1 = 0.f, s2 = 0.f;
#pragma unroll
    for (int i = 0; i < 3; ++i) {
      int j = lane + i * 64;
      float4 r = r4[j];
      s0 += dot4(r, v0[j]);
      s1 += dot4(r, v1[j]);
      s2 += dot4(r, v2[j]);
    }
    s0 = wred(s0); s1 = wred(s1); s2 = wred(s2);
    if (lane == 0) U4[k] = make_float4(s0, s1, s2, 0.f);
  }
  gbar(bars, 1);

  // ---- stage C: T[m][a][j] = x0[m] . U_a[:,j] (9 scalars; 1 node per wave) --
  {
    int m = w;  // 2112 waves = NNODES
    int tok = (m < NDOCS) ? doc_ids[m * TITLE_LEN]
            : (m < NDOCS + NPASS) ? pass_ids[(m - NDOCS) * SEQ]
                                  : SPAN_TOK;
    const float4* e4 = (const float4*)(embed + (size_t)tok * DIM);
    float s[9] = {};
#pragma unroll
    for (int i = 0; i < 3; ++i) {
      int j = lane + i * 64;
      float4 ev = e4[j];
#pragma unroll
      for (int q = 0; q < 4; ++q) {
        int k = j * 4 + q;
        float e1 = (q == 0) ? ev.x : (q == 1) ? ev.y : (q == 2) ? ev.z : ev.w;
        float4 u0 = U4[k], u1 = U4[DIM + k], u2 = U4[2 * DIM + k];
        s[0] += e1 * u0.x; s[1] += e1 * u0.y; s[2] += e1 * u0.z;
        s[3] += e1 * u1.x; s[4] += e1 * u1.y; s[5] += e1 * u1.z;
        s[6] += e1 * u2.x; s[7] += e1 * u2.y; s[8] += e1 * u2.z;
      }
    }
#pragma unroll
    for (int a = 0; a < 9; ++a) s[a] = wred(s[a]);
    if (lane == 0) {
      Tq[m * 4 + 0] = make_float4(s[0], s[1], s[2], 0.f);
      Tq[m * 4 + 1] = make_float4(s[3], s[4], s[5], 0.f);
      Tq[m * 4 + 2] = make_float4(s[6], s[7], s[8], 0.f);
    }
  }
  gbar(bars, 2);

  // ---- stage D: accP[d][j][r] += T[src][1+r][j] (edge-parallel) ----
  if (gtid < NEDGES) {
    int s = src[gtid], d = dst[gtid], r = et[gtid];
    float4 t = Tq[s * 4 + 1 + r];
    atomicAdd(&accP[d * 6 + 0 + r], t.x);
    atomicAdd(&accP[d * 6 + 2 + r], t.y);
    atomicAdd(&accP[d * 6 + 4 + r], t.z);
  }
  gbar(bars, 3);

  // ---- stage E: zacc[d][r] += P[src][1+r] (span-destined edges) ----
  if (gtid < NEDGES) {
    int d = dst[gtid];
    if (d >= SPAN0) {
      int s = src[gtid], r = et[gtid];
      int j = 1 + r;
      float i0 = 1.f / fmaxf((float)deg[s], 1.f);
      float i1 = 1.f / fmaxf((float)deg[NNODES + s], 1.f);
      float t0j = ((const float*)(Tq + (size_t)s * 4))[j];
      float a0 = accP[s * 6 + j * 2 + 0];
      float a1 = accP[s * 6 + j * 2 + 1];
      float dj = ((const float*)(U4 + 3 * DIM))[j];
      float P = t0j + a0 * i0 + a1 * i1 + dj;
      atomicAdd(&zacc[(d - SPAN0) * 2 + r], P);
    }
  }
  gbar(bars, 4);

  // ---- stage F: out[i] = exp(sigmoid(z)/TAU) ----
  if (gtid < NPASS) {
    int i = gtid;
    int n = SPAN0 + i;
    float i0 = 1.f / fmaxf((float)deg[n], 1.f);
    float i1 = 1.f / fmaxf((float)deg[NNODES + n], 1.f);
    float P0 = Tq[n * 4].x + accP[n * 6 + 0] * i0 + accP[n * 6 + 1] * i1 +
               U4[3 * DIM].x;
    float z = P0 + zacc[i * 2 + 0] * i0 + zacc[i * 2 + 1] * i1 + v[3 * DIM];
    float sc = 1.f / (1.f + expf(-z));
    out[i] = expf(sc * 5.f);  // exp(score / TAU), TAU = 0.2
  }
}

extern "C" void kernel_launch(void* const* d_in, const int* in_sizes, int n_in,
                              void* d_out, int out_size, void* d_ws, size_t ws_size,
                              hipStream_t stream) {
  const int* doc_ids = (const int*)d_in[0];
  const int* pass_ids = (const int*)d_in[1];
  const int* edge_index = (const int*)d_in[2];
  const int* etype = (const int*)d_in[3];
  const float* embed = (const float*)d_in[4];
  const float* w_root1 = (const float*)d_in[5];
  const float* w_rel1 = (const float*)d_in[6];
  const float* b1 = (const float*)d_in[7];
  const float* w_root2 = (const float*)d_in[8];
  const float* w_rel2 = (const float*)d_in[9];
  const float* b2 = (const float*)d_in[10];
  const float* clf_w = (const float*)d_in[11];
  const float* clf_b = (const float*)d_in[12];
  float* out = (float*)d_out;

  const int* src = edge_index;
  const int* dst = edge_index + NEDGES;

  float4* U4 = (float4*)d_ws;                    // 2305 float4
  float4* Tq = U4 + (3 * DIM + 1);               // NNODES*4 float4
  float* v = (float*)(Tq + (size_t)NNODES * 4);  // 2305 floats
  float* accP = v + (3 * DIM + 1);               // NNODES*6  (clear region)
  float* zacc = accP + NNODES * 6;               // NPASS*2
  int* deg = (int*)(zacc + NPASS * 2);           // NBINS
  int* bars = deg + NBINS;                       // 2*NSYNC

  init_kernel<<<(CLRWORDS + 255) / 256, 256, 0, stream>>>((int*)accP);
  mega_kernel<<<NBLK, 256, 0, stream>>>(doc_ids, pass_ids, src, dst, etype,
                                        embed, w_root1, w_rel1, b1, w_root2,
                                        w_rel2, b2, clf_w, clf_b, U4, Tq, v,
                                        accP, zacc, deg, bars, out);
}

// Round 10
// 163.226 us; speedup vs baseline: 1.8957x; 1.8957x over previous
//
#include <hip/hip_runtime.h>

#define NDOCS 64
#define NPASS 1024
#define TITLE_LEN 128
#define SEQ 256
#define NEDGES 32768
#define NNODES 2112   // NDOCS + 2*NPASS
#define DIM 768
#define SPAN_TOK 30522
#define NREL 2
#define NBINS (NREL * NNODES)   // 4224
#define SPAN0 (NNODES - NPASS)  // 1088
#define NBLK 528                // 528 blocks * 4 waves = 2112 waves
#define NSYNC 5
// clear region: accP (NNODES*6) | zacc (NPASS*2) | deg (NBINS) | bars (2*NSYNC)
#define CLRWORDS (NNODES * 6 + NPASS * 2 + NBINS + 2 * NSYNC)

__device__ inline float wred(float s) {
#pragma unroll
  for (int off = 32; off > 0; off >>= 1) s += __shfl_down(s, off);
  return s;
}
__device__ inline float dot4(float4 a, float4 b) {
  return a.x * b.x + a.y * b.y + a.z * b.z + a.w * b.w;
}

// grid barrier, coherence-cheap: RELEASE arrival add; RELAXED polling (no
// cache ops per iteration); single ACQUIRE once flag observed. Per-sync
// {cnt, flag} zeroed by init_kernel each launch.
__device__ inline void gbar(int* bars, int i) {
  __syncthreads();
  if (threadIdx.x == 0) {
    int* cnt = &bars[2 * i];
    int* flag = &bars[2 * i + 1];
    int prev = __hip_atomic_fetch_add(cnt, 1, __ATOMIC_RELEASE,
                                      __HIP_MEMORY_SCOPE_AGENT);
    if (prev == NBLK - 1) {
      // acquire all other blocks' releases, then publish
      (void)__hip_atomic_load(cnt, __ATOMIC_ACQUIRE, __HIP_MEMORY_SCOPE_AGENT);
      __hip_atomic_store(flag, 1, __ATOMIC_RELEASE, __HIP_MEMORY_SCOPE_AGENT);
    } else {
      while (__hip_atomic_load(flag, __ATOMIC_RELAXED,
                               __HIP_MEMORY_SCOPE_AGENT) == 0)
        __builtin_amdgcn_s_sleep(4);
      (void)__hip_atomic_load(flag, __ATOMIC_ACQUIRE, __HIP_MEMORY_SCOPE_AGENT);
    }
  }
  __syncthreads();
}

__global__ __launch_bounds__(256) void init_kernel(int* __restrict__ clr) {
  int i = blockIdx.x * 256 + threadIdx.x;
  if (i < CLRWORDS) clr[i] = 0;
}

__global__ __launch_bounds__(256) void mega_kernel(
    const int* __restrict__ doc_ids, const int* __restrict__ pass_ids,
    const int* __restrict__ src, const int* __restrict__ dst,
    const int* __restrict__ et, const float* __restrict__ embed,
    const float* __restrict__ w_root1, const float* __restrict__ w_rel1,
    const float* __restrict__ b1, const float* __restrict__ w_root2,
    const float* __restrict__ w_rel2, const float* __restrict__ b2,
    const float* __restrict__ clf_w, const float* __restrict__ clf_b,
    float4* __restrict__ U4, float4* __restrict__ Tq, float* __restrict__ v,
    float* __restrict__ accP, float* __restrict__ zacc, int* __restrict__ deg,
    int* __restrict__ bars, float* __restrict__ out) {
  const int w = blockIdx.x * 4 + (threadIdx.x >> 6);  // global wave id 0..2111
  const int lane = threadIdx.x & 63;
  const int gtid = blockIdx.x * 256 + threadIdx.x;

  // ---- stage A: foldv (v = Wcat2 . clf_w) || hist ----
  for (int k = w; k <= 3 * DIM; k += 4 * NBLK) {
    const float* row = (k < DIM) ? w_root2 + (size_t)k * DIM
                     : (k < 3 * DIM) ? w_rel2 + (size_t)(k - DIM) * DIM
                                     : b2;
    const float4* r4 = (const float4*)row;
    const float4* w4 = (const float4*)clf_w;
    float s = 0.f;
#pragma unroll
    for (int i = 0; i < 3; ++i) {
      int j = lane + i * 64;
      s += dot4(r4[j], w4[j]);
    }
    s = wred(s);
    if (lane == 0) v[k] = s + (k == 3 * DIM ? clf_b[0] : 0.f);
  }
  if (gtid < NEDGES) atomicAdd(&deg[et[gtid] * NNODES + dst[gtid]], 1);
  gbar(bars, 0);

  // ---- stage B: foldu (U4[k] = {row_k(Wcat1).v0,.v1,.v2}; U4[2304]=d) ----
  for (int k = w; k <= 3 * DIM; k += 4 * NBLK) {
    const float* row = (k < DIM) ? w_root1 + (size_t)k * DIM
                     : (k < 3 * DIM) ? w_rel1 + (size_t)(k - DIM) * DIM
                                     : b1;
    const float4* r4 = (const float4*)row;
    const float4* v0 = (const float4*)v;
    const float4* v1 = (const float4*)(v + DIM);
    const float4* v2 = (const float4*)(v + 2 * DIM);
    float s0 = 0.f, s1 = 0.f, s2 = 0.f;
#pragma unroll
    for (int i = 0; i < 3; ++i) {
      int j = lane + i * 64;
      float4 r = r4[j];
      s0 += dot4(r, v0[j]);
      s1 += dot4(r, v1[j]);
      s2 += dot4(r, v2[j]);
    }
    s0 = wred(s0); s1 = wred(s1); s2 = wred(s2);
    if (lane == 0) U4[k] = make_float4(s0, s1, s2, 0.f);
  }
  gbar(bars, 1);

  // ---- stage C: T[m][a][j] = x0[m] . U_a[:,j] (9 scalars; 1 node per wave) --
  {
    int m = w;  // 2112 waves = NNODES
    int tok = (m < NDOCS) ? doc_ids[m * TITLE_LEN]
            : (m < NDOCS + NPASS) ? pass_ids[(m - NDOCS) * SEQ]
                                  : SPAN_TOK;
    const float4* e4 = (const float4*)(embed + (size_t)tok * DIM);
    float s[9] = {};
#pragma unroll
    for (int i = 0; i < 3; ++i) {
      int j = lane + i * 64;
      float4 ev = e4[j];
#pragma unroll
      for (int q = 0; q < 4; ++q) {
        int k = j * 4 + q;
        float e1 = (q == 0) ? ev.x : (q == 1) ? ev.y : (q == 2) ? ev.z : ev.w;
        float4 u0 = U4[k], u1 = U4[DIM + k], u2 = U4[2 * DIM + k];
        s[0] += e1 * u0.x; s[1] += e1 * u0.y; s[2] += e1 * u0.z;
        s[3] += e1 * u1.x; s[4] += e1 * u1.y; s[5] += e1 * u1.z;
        s[6] += e1 * u2.x; s[7] += e1 * u2.y; s[8] += e1 * u2.z;
      }
    }
#pragma unroll
    for (int a = 0; a < 9; ++a) s[a] = wred(s[a]);
    if (lane == 0) {
      Tq[m * 4 + 0] = make_float4(s[0], s[1], s[2], 0.f);
      Tq[m * 4 + 1] = make_float4(s[3], s[4], s[5], 0.f);
      Tq[m * 4 + 2] = make_float4(s[6], s[7], s[8], 0.f);
    }
  }
  gbar(bars, 2);

  // ---- stage D: accP[d][j][r] += T[src][1+r][j] (edge-parallel) ----
  if (gtid < NEDGES) {
    int s = src[gtid], d = dst[gtid], r = et[gtid];
    float4 t = Tq[s * 4 + 1 + r];
    atomicAdd(&accP[d * 6 + 0 + r], t.x);
    atomicAdd(&accP[d * 6 + 2 + r], t.y);
    atomicAdd(&accP[d * 6 + 4 + r], t.z);
  }
  gbar(bars, 3);

  // ---- stage E: zacc[d][r] += P[src][1+r] (span-destined edges) ----
  if (gtid < NEDGES) {
    int d = dst[gtid];
    if (d >= SPAN0) {
      int s = src[gtid], r = et[gtid];
      int j = 1 + r;
      float i0 = 1.f / fmaxf((float)deg[s], 1.f);
      float i1 = 1.f / fmaxf((float)deg[NNODES + s], 1.f);
      float t0j = ((const float*)(Tq + (size_t)s * 4))[j];
      float a0 = accP[s * 6 + j * 2 + 0];
      float a1 = accP[s * 6 + j * 2 + 1];
      float dj = ((const float*)(U4 + 3 * DIM))[j];
      float P = t0j + a0 * i0 + a1 * i1 + dj;
      atomicAdd(&zacc[(d - SPAN0) * 2 + r], P);
    }
  }
  gbar(bars, 4);

  // ---- stage F: out[i] = exp(sigmoid(z)/TAU) ----
  if (gtid < NPASS) {
    int i = gtid;
    int n = SPAN0 + i;
    float i0 = 1.f / fmaxf((float)deg[n], 1.f);
    float i1 = 1.f / fmaxf((float)deg[NNODES + n], 1.f);
    float P0 = Tq[n * 4].x + accP[n * 6 + 0] * i0 + accP[n * 6 + 1] * i1 +
               U4[3 * DIM].x;
    float z = P0 + zacc[i * 2 + 0] * i0 + zacc[i * 2 + 1] * i1 + v[3 * DIM];
    float sc = 1.f / (1.f + expf(-z));
    out[i] = expf(sc * 5.f);  // exp(score / TAU), TAU = 0.2
  }
}

extern "C" void kernel_launch(void* const* d_in, const int* in_sizes, int n_in,
                              void* d_out, int out_size, void* d_ws, size_t ws_size,
                              hipStream_t stream) {
  const int* doc_ids = (const int*)d_in[0];
  const int* pass_ids = (const int*)d_in[1];
  const int* edge_index = (const int*)d_in[2];
  const int* etype = (const int*)d_in[3];
  const float* embed = (const float*)d_in[4];
  const float* w_root1 = (const float*)d_in[5];
  const float* w_rel1 = (const float*)d_in[6];
  const float* b1 = (const float*)d_in[7];
  const float* w_root2 = (const float*)d_in[8];
  const float* w_rel2 = (const float*)d_in[9];
  const float* b2 = (const float*)d_in[10];
  const float* clf_w = (const float*)d_in[11];
  const float* clf_b = (const float*)d_in[12];
  float* out = (float*)d_out;

  const int* src = edge_index;
  const int* dst = edge_index + NEDGES;

  float4* U4 = (float4*)d_ws;                    // 2305 float4
  float4* Tq = U4 + (3 * DIM + 1);               // NNODES*4 float4
  float* v = (float*)(Tq + (size_t)NNODES * 4);  // 2305 floats
  float* accP = v + (3 * DIM + 1);               // NNODES*6  (clear region)
  float* zacc = accP + NNODES * 6;               // NPASS*2
  int* deg = (int*)(zacc + NPASS * 2);           // NBINS
  int* bars = deg + NBINS;                       // 2*NSYNC

  init_kernel<<<(CLRWORDS + 255) / 256, 256, 0, stream>>>((int*)accP);
  mega_kernel<<<NBLK, 256, 0, stream>>>(doc_ids, pass_ids, src, dst, etype,
                                        embed, w_root1, w_rel1, b1, w_root2,
                                        w_rel2, b2, clf_w, clf_b, U4, Tq, v,
                                        accP, zacc, deg, bars, out);
}

// Round 12
// 39.071 us; speedup vs baseline: 7.9194x; 4.1777x over previous
//
#include <hip/hip_runtime.h>

#define NDOCS 64
#define NPASS 1024
#define TITLE_LEN 128
#define SEQ 256
#define NEDGES 32768
#define NNODES 2112   // NDOCS + 2*NPASS
#define DIM 768
#define SPAN_TOK 30522
#define NREL 2
#define NBINS (NREL * NNODES)   // 4224
#define SPAN0 (NNODES - NPASS)  // 1088
// clear region: accP (NNODES*6) | deg (NBINS) = 16896 = 66*256
#define CLRWORDS (NNODES * 6 + NBINS)

__device__ inline float wred(float s) {
#pragma unroll
  for (int off = 32; off > 0; off >>= 1) s += __shfl_down(s, off);
  return s;
}
__device__ inline float dot4(float4 a, float4 b) {
  return a.x * b.x + a.y * b.y + a.z * b.z + a.w * b.w;
}

// ---------- K1: foldv (577) | clear accP+deg (66) ----------
__global__ __launch_bounds__(256) void foldv_clear_kernel(
    const float* __restrict__ w_root2, const float* __restrict__ w_rel2,
    const float* __restrict__ b2, const float* __restrict__ clf_w,
    const float* __restrict__ clf_b, float* __restrict__ v,
    int* __restrict__ clrbase) {
  int b = blockIdx.x;
  if (b < 577) {
    int k = b * 4 + (threadIdx.x >> 6);
    int lane = threadIdx.x & 63;
    if (k > 3 * DIM) return;
    const float* row = (k < DIM) ? w_root2 + (size_t)k * DIM
                     : (k < 3 * DIM) ? w_rel2 + (size_t)(k - DIM) * DIM
                                     : b2;
    const float4* r4 = (const float4*)row;
    const float4* w4 = (const float4*)clf_w;
    float s = 0.f;
#pragma unroll
    for (int i = 0; i < 3; ++i) {
      int j = lane + i * 64;
      s += dot4(r4[j], w4[j]);
    }
    s = wred(s);
    if (lane == 0) v[k] = s + (k == 3 * DIM ? clf_b[0] : 0.f);
  } else {
    int i = (b - 577) * 256 + threadIdx.x;
    clrbase[i] = 0;  // CLRWORDS == 66*256 exactly
  }
}

// ---------- K2: hist (128) | foldu (577) ----------
__global__ __launch_bounds__(256) void hist_foldu_kernel(
    const int* __restrict__ dst, const int* __restrict__ et,
    int* __restrict__ deg, const float* __restrict__ w_root1,
    const float* __restrict__ w_rel1, const float* __restrict__ b1,
    const float* __restrict__ v, float4* __restrict__ U4) {
  int b = blockIdx.x;
  if (b < 128) {
    int e = b * 256 + threadIdx.x;
    atomicAdd(&deg[et[e] * NNODES + dst[e]], 1);
  } else {
    int k = (b - 128) * 4 + (threadIdx.x >> 6);
    int lane = threadIdx.x & 63;
    if (k > 3 * DIM) return;
    const float* row = (k < DIM) ? w_root1 + (size_t)k * DIM
                     : (k < 3 * DIM) ? w_rel1 + (size_t)(k - DIM) * DIM
                                     : b1;
    const float4* r4 = (const float4*)row;
    const float4* v0 = (const float4*)v;
    const float4* v1 = (const float4*)(v + DIM);
    const float4* v2 = (const float4*)(v + 2 * DIM);
    float s0 = 0.f, s1 = 0.f, s2 = 0.f;
#pragma unroll
    for (int i = 0; i < 3; ++i) {
      int j = lane + i * 64;
      float4 r = r4[j];
      s0 += dot4(r, v0[j]);
      s1 += dot4(r, v1[j]);
      s2 += dot4(r, v2[j]);
    }
    s0 = wred(s0); s1 = wred(s1); s2 = wred(s2);
    if (lane == 0) U4[k] = make_float4(s0, s1, s2, 0.f);
  }
}

// ---------- K3: T (528, wave/node) | scan (1 block) ----------
__global__ __launch_bounds__(256) void t_scan_kernel(
    const int* __restrict__ doc_ids, const int* __restrict__ pass_ids,
    const float* __restrict__ embed, const float4* __restrict__ U4,
    float4* __restrict__ Tq, const int* __restrict__ deg,
    int* __restrict__ offs, int* __restrict__ cur) {
  __shared__ int part[256];
  int b = blockIdx.x;
  int tid = threadIdx.x;
  if (b < 528) {
    int m = b * 4 + (tid >> 6);
    int lane = tid & 63;
    int tok = (m < NDOCS) ? doc_ids[m * TITLE_LEN]
            : (m < NDOCS + NPASS) ? pass_ids[(m - NDOCS) * SEQ]
                                  : SPAN_TOK;
    const float4* e4 = (const float4*)(embed + (size_t)tok * DIM);
    float s[9] = {};
#pragma unroll
    for (int i = 0; i < 3; ++i) {
      int j = lane + i * 64;
      float4 ev = e4[j];
#pragma unroll
      for (int q = 0; q < 4; ++q) {
        int k = j * 4 + q;
        float e1 = (q == 0) ? ev.x : (q == 1) ? ev.y : (q == 2) ? ev.z : ev.w;
        float4 u0 = U4[k], u1 = U4[DIM + k], u2 = U4[2 * DIM + k];
        s[0] += e1 * u0.x; s[1] += e1 * u0.y; s[2] += e1 * u0.z;
        s[3] += e1 * u1.x; s[4] += e1 * u1.y; s[5] += e1 * u1.z;
        s[6] += e1 * u2.x; s[7] += e1 * u2.y; s[8] += e1 * u2.z;
      }
    }
#pragma unroll
    for (int a = 0; a < 9; ++a) s[a] = wred(s[a]);
    if (lane == 0) {
      Tq[m * 4 + 0] = make_float4(s[0], s[1], s[2], 0.f);
      Tq[m * 4 + 1] = make_float4(s[3], s[4], s[5], 0.f);
      Tq[m * 4 + 2] = make_float4(s[6], s[7], s[8], 0.f);
    }
  } else {
    // exclusive scan of deg -> offs, cur (validated round-2 structure)
    int loc[17];
    int s = 0;
#pragma unroll
    for (int i = 0; i < 17; ++i) {
      int idx = tid * 17 + i;
      loc[i] = s;
      s += (idx < NBINS) ? deg[idx] : 0;
    }
    part[tid] = s;
    __syncthreads();
    for (int off = 1; off < 256; off <<= 1) {
      int val = (tid >= off) ? part[tid - off] : 0;
      __syncthreads();
      part[tid] += val;
      __syncthreads();
    }
    int pre = (tid == 0) ? 0 : part[tid - 1];
#pragma unroll
    for (int i = 0; i < 17; ++i) {
      int idx = tid * 17 + i;
      if (idx <= NBINS) {
        int val = pre + loc[i];
        offs[idx] = val;
        if (idx < NBINS) cur[idx] = val;
      }
    }
  }
}

// ---------- K4: scatter (128) | pacc (128) ----------
__global__ __launch_bounds__(256) void scatter_pacc_kernel(
    const int* __restrict__ srcv, const int* __restrict__ dst,
    const int* __restrict__ et, int* __restrict__ cur, int* __restrict__ perm,
    const float4* __restrict__ Tq, float* __restrict__ accP) {
  int b = blockIdx.x;
  if (b < 128) {
    int e = b * 256 + threadIdx.x;
    int bin = et[e] * NNODES + dst[e];
    int p = atomicAdd(&cur[bin], 1);
    perm[p] = srcv[e];
  } else {
    int e = (b - 128) * 256 + threadIdx.x;
    int s = srcv[e], d = dst[e], r = et[e];
    float4 t = Tq[s * 4 + 1 + r];
    atomicAdd(&accP[d * 6 + 0 + r], t.x);
    atomicAdd(&accP[d * 6 + 2 + r], t.y);
    atomicAdd(&accP[d * 6 + 4 + r], t.z);
  }
}

// ---------- K5: final. wave/span-node; lanes over CSR in-edges ----------
// z = P0[n] + sum_r mean_{s in bin(r,n)} P[s][1+r] + c0
// P[s][j] = T[s][0][j] + accP[s][j][0]/max(deg0,1) + accP[s][j][1]/max(deg1,1) + d_j
__global__ __launch_bounds__(256) void final_kernel(
    const float4* __restrict__ Tq, const float* __restrict__ accP,
    const int* __restrict__ offs, const int* __restrict__ perm,
    const float4* __restrict__ U4, const float* __restrict__ v,
    float* __restrict__ out) {
  int i = blockIdx.x * 4 + (threadIdx.x >> 6);  // span idx
  int lane = threadIdx.x & 63;
  int n = SPAN0 + i;
  float4 D = U4[3 * DIM];
  float zterm = 0.f;  // lane-partial of relation terms
#pragma unroll
  for (int r = 0; r < NREL; ++r) {
    int bin = r * NNODES + n;
    int beg = offs[bin], end = offs[bin + 1];
    int cnt = end - beg;
    if (cnt <= 0) continue;
    int j = 1 + r;
    float psum = 0.f;
    for (int e = beg + lane; e < end; e += 64) {
      int s = perm[e];
      float i0 = 1.f / fmaxf((float)(offs[s + 1] - offs[s]), 1.f);
      float i1 = 1.f / fmaxf((float)(offs[NNODES + s + 1] - offs[NNODES + s]), 1.f);
      const float* t0 = (const float*)(Tq + (size_t)s * 4);
      float Ps = t0[j] + accP[s * 6 + j * 2 + 0] * i0 +
                 accP[s * 6 + j * 2 + 1] * i1 + ((const float*)&D)[j];
      psum += Ps;
    }
    zterm += psum / (float)cnt;
  }
  zterm = wred(zterm);
  if (lane == 0) {
    float i0 = 1.f / fmaxf((float)(offs[n + 1] - offs[n]), 1.f);
    float i1 = 1.f / fmaxf((float)(offs[NNODES + n + 1] - offs[NNODES + n]), 1.f);
    float P0 = Tq[n * 4].x + accP[n * 6 + 0] * i0 + accP[n * 6 + 1] * i1 + D.x;
    float z = P0 + zterm + v[3 * DIM];
    float sc = 1.f / (1.f + expf(-z));
    out[i] = expf(sc * 5.f);  // exp(score / TAU), TAU = 0.2
  }
}

extern "C" void kernel_launch(void* const* d_in, const int* in_sizes, int n_in,
                              void* d_out, int out_size, void* d_ws, size_t ws_size,
                              hipStream_t stream) {
  const int* doc_ids = (const int*)d_in[0];
  const int* pass_ids = (const int*)d_in[1];
  const int* edge_index = (const int*)d_in[2];
  const int* etype = (const int*)d_in[3];
  const float* embed = (const float*)d_in[4];
  const float* w_root1 = (const float*)d_in[5];
  const float* w_rel1 = (const float*)d_in[6];
  const float* b1 = (const float*)d_in[7];
  const float* w_root2 = (const float*)d_in[8];
  const float* w_rel2 = (const float*)d_in[9];
  const float* b2 = (const float*)d_in[10];
  const float* clf_w = (const float*)d_in[11];
  const float* clf_b = (const float*)d_in[12];
  float* out = (float*)d_out;

  const int* src = edge_index;
  const int* dst = edge_index + NEDGES;

  float4* U4 = (float4*)d_ws;                    // 2305 float4
  float4* Tq = U4 + (3 * DIM + 1);               // NNODES*4 float4
  float* v = (float*)(Tq + (size_t)NNODES * 4);  // 2305 floats
  float* accP = v + (3 * DIM + 1);               // NNODES*6 (clear region)
  int* deg = (int*)(accP + NNODES * 6);          // NBINS
  int* offs = deg + NBINS;                       // NBINS + 1
  int* cur = offs + NBINS + 1;                   // NBINS
  int* perm = cur + NBINS;                       // NEDGES

  foldv_clear_kernel<<<577 + 66, 256, 0, stream>>>(w_root2, w_rel2, b2, clf_w,
                                                   clf_b, v, (int*)accP);
  hist_foldu_kernel<<<128 + 577, 256, 0, stream>>>(dst, etype, deg, w_root1,
                                                   w_rel1, b1, v, U4);
  t_scan_kernel<<<528 + 1, 256, 0, stream>>>(doc_ids, pass_ids, embed, U4, Tq,
                                             deg, offs, cur);
  scatter_pacc_kernel<<<128 + 128, 256, 0, stream>>>(src, dst, etype, cur, perm,
                                                     Tq, accP);
  final_kernel<<<NPASS / 4, 256, 0, stream>>>(Tq, accP, offs, perm, U4, v, out);
}

// Round 13
// 34.927 us; speedup vs baseline: 8.8591x; 1.1187x over previous
//
#include <hip/hip_runtime.h>

#define NDOCS 64
#define NPASS 1024
#define TITLE_LEN 128
#define SEQ 256
#define NEDGES 32768
#define NNODES 2112   // NDOCS + 2*NPASS
#define DIM 768
#define SPAN_TOK 30522
#define NREL 2
#define NBINS (NREL * NNODES)   // 4224
#define SPAN0 (NNODES - NPASS)  // 1088
#define CAP 48                  // max in-edges per (rel,node) bin; P(overflow)~1e-26

__device__ inline float wred(float s) {
#pragma unroll
  for (int off = 32; off > 0; off >>= 1) s += __shfl_down(s, off);
  return s;
}
__device__ inline float dot4(float4 a, float4 b) {
  return a.x * b.x + a.y * b.y + a.z * b.z + a.w * b.w;
}

// ---------- K1: foldv (577) | clear deg (17) ----------
// v[k] = row_k(Wcat2) . clf_w ; v[2304] = b2.clf_w + clf_b
__global__ __launch_bounds__(256) void foldv_clear_kernel(
    const float* __restrict__ w_root2, const float* __restrict__ w_rel2,
    const float* __restrict__ b2, const float* __restrict__ clf_w,
    const float* __restrict__ clf_b, float* __restrict__ v,
    int* __restrict__ deg) {
  int b = blockIdx.x;
  if (b < 577) {
    int k = b * 4 + (threadIdx.x >> 6);
    int lane = threadIdx.x & 63;
    if (k > 3 * DIM) return;
    const float* row = (k < DIM) ? w_root2 + (size_t)k * DIM
                     : (k < 3 * DIM) ? w_rel2 + (size_t)(k - DIM) * DIM
                                     : b2;
    const float4* r4 = (const float4*)row;
    const float4* w4 = (const float4*)clf_w;
    float s = 0.f;
#pragma unroll
    for (int i = 0; i < 3; ++i) {
      int j = lane + i * 64;
      s += dot4(r4[j], w4[j]);
    }
    s = wred(s);
    if (lane == 0) v[k] = s + (k == 3 * DIM ? clf_b[0] : 0.f);
  } else {
    int i = (b - 577) * 256 + threadIdx.x;
    if (i < NBINS) deg[i] = 0;
  }
}

// ---------- K2: bucket-scatter (128) | foldu (577) ----------
// bucket[bin*CAP + slot] = src, deg[bin] = count  (hist+scatter in one pass)
// U4[k] = {row_k(Wcat1).v0, .v1, .v2}; U4[2304] = d (bias fold)
__global__ __launch_bounds__(256) void bucket_foldu_kernel(
    const int* __restrict__ srcv, const int* __restrict__ dst,
    const int* __restrict__ et, int* __restrict__ deg, int* __restrict__ bucket,
    const float* __restrict__ w_root1, const float* __restrict__ w_rel1,
    const float* __restrict__ b1, const float* __restrict__ v,
    float4* __restrict__ U4) {
  int b = blockIdx.x;
  if (b < 128) {
    int e = b * 256 + threadIdx.x;
    int bin = et[e] * NNODES + dst[e];
    int slot = atomicAdd(&deg[bin], 1);
    if (slot < CAP) bucket[bin * CAP + slot] = srcv[e];
  } else {
    int k = (b - 128) * 4 + (threadIdx.x >> 6);
    int lane = threadIdx.x & 63;
    if (k > 3 * DIM) return;
    const float* row = (k < DIM) ? w_root1 + (size_t)k * DIM
                     : (k < 3 * DIM) ? w_rel1 + (size_t)(k - DIM) * DIM
                                     : b1;
    const float4* r4 = (const float4*)row;
    const float4* v0 = (const float4*)v;
    const float4* v1 = (const float4*)(v + DIM);
    const float4* v2 = (const float4*)(v + 2 * DIM);
    float s0 = 0.f, s1 = 0.f, s2 = 0.f;
#pragma unroll
    for (int i = 0; i < 3; ++i) {
      int j = lane + i * 64;
      float4 r = r4[j];
      s0 += dot4(r, v0[j]);
      s1 += dot4(r, v1[j]);
      s2 += dot4(r, v2[j]);
    }
    s0 = wred(s0); s1 = wred(s1); s2 = wred(s2);
    if (lane == 0) U4[k] = make_float4(s0, s1, s2, 0.f);
  }
}

// ---------- K3: T[m][a][j] = x0[m].U_a[:,j], m in [0,1088] ----------
// All span nodes share token SPAN_TOK -> single entry at m=1088; readers
// use min(m,1088).
__global__ __launch_bounds__(256) void t_kernel(
    const int* __restrict__ doc_ids, const int* __restrict__ pass_ids,
    const float* __restrict__ embed, const float4* __restrict__ U4,
    float4* __restrict__ Tq) {
  int m = blockIdx.x * 4 + (threadIdx.x >> 6);
  int lane = threadIdx.x & 63;
  if (m > SPAN0) return;  // 1089 entries: [0,1088] ; m==1088 is the span proto
  int tok = (m < NDOCS) ? doc_ids[m * TITLE_LEN]
          : (m < NDOCS + NPASS) ? pass_ids[(m - NDOCS) * SEQ]
                                : SPAN_TOK;
  const float4* e4 = (const float4*)(embed + (size_t)tok * DIM);
  float s[9] = {};
#pragma unroll
  for (int i = 0; i < 3; ++i) {
    int j = lane + i * 64;
    float4 ev = e4[j];
#pragma unroll
    for (int q = 0; q < 4; ++q) {
      int k = j * 4 + q;
      float e1 = (q == 0) ? ev.x : (q == 1) ? ev.y : (q == 2) ? ev.z : ev.w;
      float4 u0 = U4[k], u1 = U4[DIM + k], u2 = U4[2 * DIM + k];
      s[0] += e1 * u0.x; s[1] += e1 * u0.y; s[2] += e1 * u0.z;
      s[3] += e1 * u1.x; s[4] += e1 * u1.y; s[5] += e1 * u1.z;
      s[6] += e1 * u2.x; s[7] += e1 * u2.y; s[8] += e1 * u2.z;
    }
  }
#pragma unroll
  for (int a = 0; a < 9; ++a) s[a] = wred(s[a]);
  if (lane == 0) {
    Tq[m * 4 + 0] = make_float4(s[0], s[1], s[2], 0.f);
    Tq[m * 4 + 1] = make_float4(s[3], s[4], s[5], 0.f);
    Tq[m * 4 + 2] = make_float4(s[6], s[7], s[8], 0.f);
  }
}

// ---------- K4: final, 2-level traversal. wave/span-node ----------
// z = T[n][0][0] + D[0] + c0 + sum_{own edges (s,r)} i_r(n) * (
//       T[s][1+r][0]                      (P0[n] mean term)
//     + T[s][0][1+r] + D[1+r]             (P[s][1+r] base)
//     + sum_{r'} mean_{s' in bin(r',s)} T[s'][1+r'][1+r] )
// Tq float layout: Tqf[m*16 + a*4 + j]; reader index min(m,1088).
__global__ __launch_bounds__(256) void final_kernel(
    const float4* __restrict__ Tq, const int* __restrict__ deg,
    const int* __restrict__ bucket, const float4* __restrict__ U4,
    const float* __restrict__ v, float* __restrict__ out) {
  int i = blockIdx.x * 4 + (threadIdx.x >> 6);  // span idx 0..1023
  int lane = threadIdx.x & 63;
  int n = SPAN0 + i;
  const float* Tqf = (const float*)Tq;
  float4 D = U4[3 * DIM];
  const float* Df = (const float*)&D;
  int c0n = deg[n], c1n = deg[NNODES + n];
  float i0n = 1.f / fmaxf((float)c0n, 1.f);
  float i1n = 1.f / fmaxf((float)c1n, 1.f);
  int tot = c0n + c1n;
  float zpart = 0.f;
  for (int o = lane; o < tot; o += 64) {
    int r = (o < c0n) ? 0 : 1;
    int oo = (o < c0n) ? o : o - c0n;
    int s = bucket[(r * NNODES + n) * CAP + oo];
    int j = 1 + r;
    int ts = (s < SPAN0) ? s : SPAN0;
    float inner = Tqf[ts * 16 + j * 4 + 0]  // T[s][1+r][0]
                + Tqf[ts * 16 + j]          // T[s][0][1+r]
                + Df[j];
#pragma unroll
    for (int rp = 0; rp < 2; ++rp) {
      int cs = deg[rp * NNODES + s];
      float ssum = 0.f;
      for (int e = 0; e < cs; ++e) {
        int sp = bucket[(rp * NNODES + s) * CAP + e];
        int tsp = (sp < SPAN0) ? sp : SPAN0;
        ssum += Tqf[tsp * 16 + (1 + rp) * 4 + j];
      }
      inner += ssum / fmaxf((float)cs, 1.f);
    }
    zpart += ((r == 0) ? i0n : i1n) * inner;
  }
  zpart = wred(zpart);
  if (lane == 0) {
    float z = Tqf[SPAN0 * 16 + 0] + Df[0] + v[3 * DIM] + zpart;
    float sc = 1.f / (1.f + expf(-z));
    out[i] = expf(sc * 5.f);  // exp(score / TAU), TAU = 0.2
  }
}

extern "C" void kernel_launch(void* const* d_in, const int* in_sizes, int n_in,
                              void* d_out, int out_size, void* d_ws, size_t ws_size,
                              hipStream_t stream) {
  const int* doc_ids = (const int*)d_in[0];
  const int* pass_ids = (const int*)d_in[1];
  const int* edge_index = (const int*)d_in[2];
  const int* etype = (const int*)d_in[3];
  const float* embed = (const float*)d_in[4];
  const float* w_root1 = (const float*)d_in[5];
  const float* w_rel1 = (const float*)d_in[6];
  const float* b1 = (const float*)d_in[7];
  const float* w_root2 = (const float*)d_in[8];
  const float* w_rel2 = (const float*)d_in[9];
  const float* b2 = (const float*)d_in[10];
  const float* clf_w = (const float*)d_in[11];
  const float* clf_b = (const float*)d_in[12];
  float* out = (float*)d_out;

  const int* src = edge_index;
  const int* dst = edge_index + NEDGES;

  float4* U4 = (float4*)d_ws;                      // 2305 float4
  float4* Tq = U4 + (3 * DIM + 1);                 // 1089*4 float4
  float* v = (float*)(Tq + (size_t)(SPAN0 + 1) * 4);  // 2305 floats
  int* deg = (int*)(v + 3 * DIM + 1);              // NBINS
  int* bucket = deg + NBINS;                       // NBINS * CAP

  foldv_clear_kernel<<<577 + 17, 256, 0, stream>>>(w_root2, w_rel2, b2, clf_w,
                                                   clf_b, v, deg);
  bucket_foldu_kernel<<<128 + 577, 256, 0, stream>>>(src, dst, etype, deg,
                                                     bucket, w_root1, w_rel1,
                                                     b1, v, U4);
  t_kernel<<<273, 256, 0, stream>>>(doc_ids, pass_ids, embed, U4, Tq);
  final_kernel<<<NPASS / 4, 256, 0, stream>>>(Tq, deg, bucket, U4, v, out);
}

// Round 14
// 33.357 us; speedup vs baseline: 9.2761x; 1.0471x over previous
//
#include <hip/hip_runtime.h>

#define NDOCS 64
#define NPASS 1024
#define TITLE_LEN 128
#define SEQ 256
#define NEDGES 32768
#define NNODES 2112   // NDOCS + 2*NPASS
#define DIM 768
#define SPAN_TOK 30522
#define NREL 2
#define NBINS (NREL * NNODES)   // 4224
#define SPAN0 (NNODES - NPASS)  // 1088
#define CAP 48                  // max in-edges per (rel,node) bin; P(overflow)~1e-26

__device__ inline float wred(float s) {
#pragma unroll
  for (int off = 32; off > 0; off >>= 1) s += __shfl_down(s, off);
  return s;
}
__device__ inline float dot4(float4 a, float4 b) {
  return a.x * b.x + a.y * b.y + a.z * b.z + a.w * b.w;
}

// ---------- K1: foldv (577) | clear deg (17) ----------
// v[k] = row_k(Wcat2) . clf_w ; v[2304] = b2.clf_w + clf_b
__global__ __launch_bounds__(256) void foldv_clear_kernel(
    const float* __restrict__ w_root2, const float* __restrict__ w_rel2,
    const float* __restrict__ b2, const float* __restrict__ clf_w,
    const float* __restrict__ clf_b, float* __restrict__ v,
    int* __restrict__ deg) {
  int b = blockIdx.x;
  if (b < 577) {
    int k = b * 4 + (threadIdx.x >> 6);
    int lane = threadIdx.x & 63;
    if (k > 3 * DIM) return;
    const float* row = (k < DIM) ? w_root2 + (size_t)k * DIM
                     : (k < 3 * DIM) ? w_rel2 + (size_t)(k - DIM) * DIM
                                     : b2;
    const float4* r4 = (const float4*)row;
    const float4* w4 = (const float4*)clf_w;
    float s = 0.f;
#pragma unroll
    for (int i = 0; i < 3; ++i) {
      int j = lane + i * 64;
      s += dot4(r4[j], w4[j]);
    }
    s = wred(s);
    if (lane == 0) v[k] = s + (k == 3 * DIM ? clf_b[0] : 0.f);
  } else {
    int i = (b - 577) * 256 + threadIdx.x;
    if (i < NBINS) deg[i] = 0;
  }
}

// ---------- K2: bucket-scatter (128) | foldu (577) ----------
// bucket[bin*CAP + slot] = src, deg[bin] = count  (hist+scatter in one pass)
// U4[k] = {row_k(Wcat1).v0, .v1, .v2}; U4[2304] = d (bias fold)
__global__ __launch_bounds__(256) void bucket_foldu_kernel(
    const int* __restrict__ srcv, const int* __restrict__ dst,
    const int* __restrict__ et, int* __restrict__ deg, int* __restrict__ bucket,
    const float* __restrict__ w_root1, const float* __restrict__ w_rel1,
    const float* __restrict__ b1, const float* __restrict__ v,
    float4* __restrict__ U4) {
  int b = blockIdx.x;
  if (b < 128) {
    int e = b * 256 + threadIdx.x;
    int bin = et[e] * NNODES + dst[e];
    int slot = atomicAdd(&deg[bin], 1);
    if (slot < CAP) bucket[bin * CAP + slot] = srcv[e];
  } else {
    int k = (b - 128) * 4 + (threadIdx.x >> 6);
    int lane = threadIdx.x & 63;
    if (k > 3 * DIM) return;
    const float* row = (k < DIM) ? w_root1 + (size_t)k * DIM
                     : (k < 3 * DIM) ? w_rel1 + (size_t)(k - DIM) * DIM
                                     : b1;
    const float4* r4 = (const float4*)row;
    const float4* v0 = (const float4*)v;
    const float4* v1 = (const float4*)(v + DIM);
    const float4* v2 = (const float4*)(v + 2 * DIM);
    float s0 = 0.f, s1 = 0.f, s2 = 0.f;
#pragma unroll
    for (int i = 0; i < 3; ++i) {
      int j = lane + i * 64;
      float4 r = r4[j];
      s0 += dot4(r, v0[j]);
      s1 += dot4(r, v1[j]);
      s2 += dot4(r, v2[j]);
    }
    s0 = wred(s0); s1 = wred(s1); s2 = wred(s2);
    if (lane == 0) U4[k] = make_float4(s0, s1, s2, 0.f);
  }
}

// ---------- K3: T[m][a][j] = x0[m].U_a[:,j], m in [0,1088] ----------
// All span nodes share token SPAN_TOK -> single proto entry at m=1088;
// readers use min(m,1088).
__global__ __launch_bounds__(256) void t_kernel(
    const int* __restrict__ doc_ids, const int* __restrict__ pass_ids,
    const float* __restrict__ embed, const float4* __restrict__ U4,
    float4* __restrict__ Tq) {
  int m = blockIdx.x * 4 + (threadIdx.x >> 6);
  int lane = threadIdx.x & 63;
  if (m > SPAN0) return;
  int tok = (m < NDOCS) ? doc_ids[m * TITLE_LEN]
          : (m < NDOCS + NPASS) ? pass_ids[(m - NDOCS) * SEQ]
                                : SPAN_TOK;
  const float4* e4 = (const float4*)(embed + (size_t)tok * DIM);
  float s[9] = {};
#pragma unroll
  for (int i = 0; i < 3; ++i) {
    int j = lane + i * 64;
    float4 ev = e4[j];
#pragma unroll
    for (int q = 0; q < 4; ++q) {
      int k = j * 4 + q;
      float e1 = (q == 0) ? ev.x : (q == 1) ? ev.y : (q == 2) ? ev.z : ev.w;
      float4 u0 = U4[k], u1 = U4[DIM + k], u2 = U4[2 * DIM + k];
      s[0] += e1 * u0.x; s[1] += e1 * u0.y; s[2] += e1 * u0.z;
      s[3] += e1 * u1.x; s[4] += e1 * u1.y; s[5] += e1 * u1.z;
      s[6] += e1 * u2.x; s[7] += e1 * u2.y; s[8] += e1 * u2.z;
    }
  }
#pragma unroll
  for (int a = 0; a < 9; ++a) s[a] = wred(s[a]);
  if (lane == 0) {
    Tq[m * 4 + 0] = make_float4(s[0], s[1], s[2], 0.f);
    Tq[m * 4 + 1] = make_float4(s[3], s[4], s[5], 0.f);
    Tq[m * 4 + 2] = make_float4(s[6], s[7], s[8], 0.f);
  }
}

// ---------- K4: final, flattened 2-level traversal. wave/span-node ----------
// z = T[n][0][0] + D[0] + c0 + sum_{own edges (s,r)} i_r(n) * (
//       T[s][1+r][0] + T[s][0][1+r] + D[1+r]
//     + sum_{rp} mean_{s' in bin(rp,s)} T[s'][1+rp][1+r] )
// Lane layout: 4 lanes per outer edge (o = lane>>2 (+16/iter), q = lane&3).
// q-lanes stride-4 over each source's inner bins; partials / max(cs,1)
// distribute the mean; base terms added by q==0 only.
__global__ __launch_bounds__(256) void final_kernel(
    const float4* __restrict__ Tq, const int* __restrict__ deg,
    const int* __restrict__ bucket, const float4* __restrict__ U4,
    const float* __restrict__ v, float* __restrict__ out) {
  int i = blockIdx.x * 4 + (threadIdx.x >> 6);  // span idx 0..1023
  int lane = threadIdx.x & 63;
  int n = SPAN0 + i;
  const float* Tqf = (const float*)Tq;
  float4 D = U4[3 * DIM];
  const float* Df = (const float*)&D;
  int c0n = deg[n], c1n = deg[NNODES + n];
  float i0n = 1.f / fmaxf((float)c0n, 1.f);
  float i1n = 1.f / fmaxf((float)c1n, 1.f);
  int tot = c0n + c1n;
  int q = lane & 3;
  float zpart = 0.f;
  for (int o = lane >> 2; o < tot; o += 16) {
    int r = (o < c0n) ? 0 : 1;
    int oo = (o < c0n) ? o : o - c0n;
    int s = bucket[(r * NNODES + n) * CAP + oo];
    int j = 1 + r;
    int ts = (s < SPAN0) ? s : SPAN0;
    float contrib = 0.f;
    if (q == 0)
      contrib = Tqf[ts * 16 + j * 4 + 0]  // T[s][1+r][0]
              + Tqf[ts * 16 + j]          // T[s][0][1+r]
              + Df[j];
#pragma unroll
    for (int rp = 0; rp < 2; ++rp) {
      int cs = deg[rp * NNODES + s];
      float ssum = 0.f;
      for (int e = q; e < cs; e += 4) {
        int sp = bucket[(rp * NNODES + s) * CAP + e];
        int tsp = (sp < SPAN0) ? sp : SPAN0;
        ssum += Tqf[tsp * 16 + (1 + rp) * 4 + j];
      }
      contrib += ssum / fmaxf((float)cs, 1.f);
    }
    zpart += ((r == 0) ? i0n : i1n) * contrib;
  }
  zpart = wred(zpart);
  if (lane == 0) {
    float z = Tqf[SPAN0 * 16 + 0] + Df[0] + v[3 * DIM] + zpart;
    float sc = 1.f / (1.f + expf(-z));
    out[i] = expf(sc * 5.f);  // exp(score / TAU), TAU = 0.2
  }
}

extern "C" void kernel_launch(void* const* d_in, const int* in_sizes, int n_in,
                              void* d_out, int out_size, void* d_ws, size_t ws_size,
                              hipStream_t stream) {
  const int* doc_ids = (const int*)d_in[0];
  const int* pass_ids = (const int*)d_in[1];
  const int* edge_index = (const int*)d_in[2];
  const int* etype = (const int*)d_in[3];
  const float* embed = (const float*)d_in[4];
  const float* w_root1 = (const float*)d_in[5];
  const float* w_rel1 = (const float*)d_in[6];
  const float* b1 = (const float*)d_in[7];
  const float* w_root2 = (const float*)d_in[8];
  const float* w_rel2 = (const float*)d_in[9];
  const float* b2 = (const float*)d_in[10];
  const float* clf_w = (const float*)d_in[11];
  const float* clf_b = (const float*)d_in[12];
  float* out = (float*)d_out;

  const int* src = edge_index;
  const int* dst = edge_index + NEDGES;

  float4* U4 = (float4*)d_ws;                      // 2305 float4
  float4* Tq = U4 + (3 * DIM + 1);                 // 1089*4 float4
  float* v = (float*)(Tq + (size_t)(SPAN0 + 1) * 4);  // 2305 floats
  int* deg = (int*)(v + 3 * DIM + 1);              // NBINS
  int* bucket = deg + NBINS;                       // NBINS * CAP

  foldv_clear_kernel<<<577 + 17, 256, 0, stream>>>(w_root2, w_rel2, b2, clf_w,
                                                   clf_b, v, deg);
  bucket_foldu_kernel<<<128 + 577, 256, 0, stream>>>(src, dst, etype, deg,
                                                     bucket, w_root1, w_rel1,
                                                     b1, v, U4);
  t_kernel<<<273, 256, 0, stream>>>(doc_ids, pass_ids, embed, U4, Tq);
  final_kernel<<<NPASS / 4, 256, 0, stream>>>(Tq, deg, bucket, U4, v, out);
}

// Round 15
// 30.958 us; speedup vs baseline: 9.9949x; 1.0775x over previous
//
#include <hip/hip_runtime.h>

#define NDOCS 64
#define NPASS 1024
#define TITLE_LEN 128
#define SEQ 256
#define NEDGES 32768
#define NNODES 2112   // NDOCS + 2*NPASS
#define DIM 768
#define SPAN_TOK 30522
#define NREL 2
#define NBINS (NREL * NNODES)   // 4224
#define SPAN0 (NNODES - NPASS)  // 1088
#define CAP 48                  // max in-edges per (rel,node) bin; P(overflow)~1e-26

__device__ inline float wred(float s) {
#pragma unroll
  for (int off = 32; off > 0; off >>= 1) s += __shfl_down(s, off);
  return s;
}
__device__ inline float dot4(float4 a, float4 b) {
  return a.x * b.x + a.y * b.y + a.z * b.z + a.w * b.w;
}

// ---------- K1: foldv (577) | clear deg (17) ----------
// v[k] = row_k(Wcat2) . clf_w ; v[2304] = b2.clf_w + clf_b
__global__ __launch_bounds__(256) void foldv_clear_kernel(
    const float* __restrict__ w_root2, const float* __restrict__ w_rel2,
    const float* __restrict__ b2, const float* __restrict__ clf_w,
    const float* __restrict__ clf_b, float* __restrict__ v,
    int* __restrict__ deg) {
  int b = blockIdx.x;
  if (b < 577) {
    int k = b * 4 + (threadIdx.x >> 6);
    int lane = threadIdx.x & 63;
    if (k > 3 * DIM) return;
    const float* row = (k < DIM) ? w_root2 + (size_t)k * DIM
                     : (k < 3 * DIM) ? w_rel2 + (size_t)(k - DIM) * DIM
                                     : b2;
    const float4* r4 = (const float4*)row;
    const float4* w4 = (const float4*)clf_w;
    float s = 0.f;
#pragma unroll
    for (int i = 0; i < 3; ++i) {
      int j = lane + i * 64;
      s += dot4(r4[j], w4[j]);
    }
    s = wred(s);
    if (lane == 0) v[k] = s + (k == 3 * DIM ? clf_b[0] : 0.f);
  } else {
    int i = (b - 577) * 256 + threadIdx.x;
    if (i < NBINS) deg[i] = 0;
  }
}

// ---------- K2: bucket-scatter (128) | foldu (577) ----------
// bucket[bin*CAP + slot] = src, deg[bin] = count  (hist+scatter in one pass)
// U4[k] = {row_k(Wcat1).v0, .v1, .v2}; U4[2304] = d (bias fold)
__global__ __launch_bounds__(256) void bucket_foldu_kernel(
    const int* __restrict__ srcv, const int* __restrict__ dst,
    const int* __restrict__ et, int* __restrict__ deg, int* __restrict__ bucket,
    const float* __restrict__ w_root1, const float* __restrict__ w_rel1,
    const float* __restrict__ b1, const float* __restrict__ v,
    float4* __restrict__ U4) {
  int b = blockIdx.x;
  if (b < 128) {
    int e = b * 256 + threadIdx.x;
    int bin = et[e] * NNODES + dst[e];
    int slot = atomicAdd(&deg[bin], 1);
    if (slot < CAP) bucket[bin * CAP + slot] = srcv[e];
  } else {
    int k = (b - 128) * 4 + (threadIdx.x >> 6);
    int lane = threadIdx.x & 63;
    if (k > 3 * DIM) return;
    const float* row = (k < DIM) ? w_root1 + (size_t)k * DIM
                     : (k < 3 * DIM) ? w_rel1 + (size_t)(k - DIM) * DIM
                                     : b1;
    const float4* r4 = (const float4*)row;
    const float4* v0 = (const float4*)v;
    const float4* v1 = (const float4*)(v + DIM);
    const float4* v2 = (const float4*)(v + 2 * DIM);
    float s0 = 0.f, s1 = 0.f, s2 = 0.f;
#pragma unroll
    for (int i = 0; i < 3; ++i) {
      int j = lane + i * 64;
      float4 r = r4[j];
      s0 += dot4(r, v0[j]);
      s1 += dot4(r, v1[j]);
      s2 += dot4(r, v2[j]);
    }
    s0 = wred(s0); s1 = wred(s1); s2 = wred(s2);
    if (lane == 0) U4[k] = make_float4(s0, s1, s2, 0.f);
  }
}

// ---------- K3: T[m][a][j] = x0[m].U_a[:,j], one 256-thr block per node ------
// m in [0,1088]; m==1088 is the shared span prototype (token SPAN_TOK).
// Threads 0..191 each own one float4 (4 k's) of the 768-dim; 4-wave LDS reduce.
__global__ __launch_bounds__(256) void t_kernel(
    const int* __restrict__ doc_ids, const int* __restrict__ pass_ids,
    const float* __restrict__ embed, const float4* __restrict__ U4,
    float4* __restrict__ Tq) {
  __shared__ float sred[4][9];
  int m = blockIdx.x;  // 0..1088
  int t = threadIdx.x;
  int wv = t >> 6, lane = t & 63;
  int tok = (m < NDOCS) ? doc_ids[m * TITLE_LEN]
          : (m < NDOCS + NPASS) ? pass_ids[(m - NDOCS) * SEQ]
                                : SPAN_TOK;
  float s[9] = {};
  if (t < 192) {
    const float4* e4 = (const float4*)(embed + (size_t)tok * DIM);
    float4 ev = e4[t];
#pragma unroll
    for (int q = 0; q < 4; ++q) {
      int k = t * 4 + q;
      float e1 = (q == 0) ? ev.x : (q == 1) ? ev.y : (q == 2) ? ev.z : ev.w;
      float4 u0 = U4[k], u1 = U4[DIM + k], u2 = U4[2 * DIM + k];
      s[0] += e1 * u0.x; s[1] += e1 * u0.y; s[2] += e1 * u0.z;
      s[3] += e1 * u1.x; s[4] += e1 * u1.y; s[5] += e1 * u1.z;
      s[6] += e1 * u2.x; s[7] += e1 * u2.y; s[8] += e1 * u2.z;
    }
  }
#pragma unroll
  for (int a = 0; a < 9; ++a) s[a] = wred(s[a]);
  if (lane == 0) {
#pragma unroll
    for (int a = 0; a < 9; ++a) sred[wv][a] = s[a];
  }
  __syncthreads();
  if (t == 0) {
    float r[9];
#pragma unroll
    for (int a = 0; a < 9; ++a)
      r[a] = sred[0][a] + sred[1][a] + sred[2][a] + sred[3][a];
    Tq[m * 4 + 0] = make_float4(r[0], r[1], r[2], 0.f);
    Tq[m * 4 + 1] = make_float4(r[3], r[4], r[5], 0.f);
    Tq[m * 4 + 2] = make_float4(r[6], r[7], r[8], 0.f);
  }
}

// ---------- K4: final, flattened traversal; one 128-thr block per span node --
// z = T[n][0][0] + D[0] + c0 + sum_{own edges (s,r)} i_r(n) * (
//       T[s][1+r][0] + T[s][0][1+r] + D[1+r]
//     + sum_{rp} mean_{s' in bin(rp,s)} T[s'][1+rp][1+r] )
// 4 lanes per outer edge (o = t>>2, stride 32); q-lanes stride-4 over inner
// bins; division by max(cs,1) distributes the mean; 2-wave LDS reduce.
__global__ __launch_bounds__(128) void final_kernel(
    const float4* __restrict__ Tq, const int* __restrict__ deg,
    const int* __restrict__ bucket, const float4* __restrict__ U4,
    const float* __restrict__ v, float* __restrict__ out) {
  __shared__ float red2[2];
  int i = blockIdx.x;  // span idx 0..1023
  int t = threadIdx.x;
  int lane = t & 63, wv = t >> 6;
  int n = SPAN0 + i;
  const float* Tqf = (const float*)Tq;
  float4 D = U4[3 * DIM];
  const float* Df = (const float*)&D;
  int c0n = deg[n], c1n = deg[NNODES + n];
  float i0n = 1.f / fmaxf((float)c0n, 1.f);
  float i1n = 1.f / fmaxf((float)c1n, 1.f);
  int tot = c0n + c1n;
  int q = t & 3;
  float zpart = 0.f;
  for (int o = t >> 2; o < tot; o += 32) {
    int r = (o < c0n) ? 0 : 1;
    int oo = (o < c0n) ? o : o - c0n;
    int s = bucket[(r * NNODES + n) * CAP + oo];
    int j = 1 + r;
    int ts = (s < SPAN0) ? s : SPAN0;
    float contrib = 0.f;
    if (q == 0)
      contrib = Tqf[ts * 16 + j * 4 + 0]  // T[s][1+r][0]
              + Tqf[ts * 16 + j]          // T[s][0][1+r]
              + Df[j];
#pragma unroll
    for (int rp = 0; rp < 2; ++rp) {
      int cs = deg[rp * NNODES + s];
      float ssum = 0.f;
      for (int e = q; e < cs; e += 4) {
        int sp = bucket[(rp * NNODES + s) * CAP + e];
        int tsp = (sp < SPAN0) ? sp : SPAN0;
        ssum += Tqf[tsp * 16 + (1 + rp) * 4 + j];
      }
      contrib += ssum / fmaxf((float)cs, 1.f);
    }
    zpart += ((r == 0) ? i0n : i1n) * contrib;
  }
  zpart = wred(zpart);
  if (lane == 0) red2[wv] = zpart;
  __syncthreads();
  if (t == 0) {
    float z = Tqf[SPAN0 * 16 + 0] + Df[0] + v[3 * DIM] + red2[0] + red2[1];
    float sc = 1.f / (1.f + expf(-z));
    out[i] = expf(sc * 5.f);  // exp(score / TAU), TAU = 0.2
  }
}

extern "C" void kernel_launch(void* const* d_in, const int* in_sizes, int n_in,
                              void* d_out, int out_size, void* d_ws, size_t ws_size,
                              hipStream_t stream) {
  const int* doc_ids = (const int*)d_in[0];
  const int* pass_ids = (const int*)d_in[1];
  const int* edge_index = (const int*)d_in[2];
  const int* etype = (const int*)d_in[3];
  const float* embed = (const float*)d_in[4];
  const float* w_root1 = (const float*)d_in[5];
  const float* w_rel1 = (const float*)d_in[6];
  const float* b1 = (const float*)d_in[7];
  const float* w_root2 = (const float*)d_in[8];
  const float* w_rel2 = (const float*)d_in[9];
  const float* b2 = (const float*)d_in[10];
  const float* clf_w = (const float*)d_in[11];
  const float* clf_b = (const float*)d_in[12];
  float* out = (float*)d_out;

  const int* src = edge_index;
  const int* dst = edge_index + NEDGES;

  float4* U4 = (float4*)d_ws;                      // 2305 float4
  float4* Tq = U4 + (3 * DIM + 1);                 // 1089*4 float4
  float* v = (float*)(Tq + (size_t)(SPAN0 + 1) * 4);  // 2305 floats
  int* deg = (int*)(v + 3 * DIM + 1);              // NBINS
  int* bucket = deg + NBINS;                       // NBINS * CAP

  foldv_clear_kernel<<<577 + 17, 256, 0, stream>>>(w_root2, w_rel2, b2, clf_w,
                                                   clf_b, v, deg);
  bucket_foldu_kernel<<<128 + 577, 256, 0, stream>>>(src, dst, etype, deg,
                                                     bucket, w_root1, w_rel1,
                                                     b1, v, U4);
  t_kernel<<<SPAN0 + 1, 256, 0, stream>>>(doc_ids, pass_ids, embed, U4, Tq);
  final_kernel<<<NPASS, 128, 0, stream>>>(Tq, deg, bucket, U4, v, out);
}

// Round 16
// 30.619 us; speedup vs baseline: 10.1055x; 1.0111x over previous
//
#include <hip/hip_runtime.h>

#define NDOCS 64
#define NPASS 1024
#define TITLE_LEN 128
#define SEQ 256
#define NEDGES 32768
#define NNODES 2112   // NDOCS + 2*NPASS
#define DIM 768
#define SPAN_TOK 30522
#define NREL 2
#define NBINS (NREL * NNODES)   // 4224
#define SPAN0 (NNODES - NPASS)  // 1088
#define CAP 48                  // max in-edges per (rel,node) bin; P(overflow)~1e-26
#define NROWS (3 * DIM + 1)     // 2305 fold rows (incl. bias row)
#define SCATB 171               // ceil(NEDGES/192)

__device__ inline float wred(float s) {
#pragma unroll
  for (int off = 32; off > 0; off >>= 1) s += __shfl_down(s, off);
  return s;
}
__device__ inline float dot4(float4 a, float4 b) {
  return a.x * b.x + a.y * b.y + a.z * b.z + a.w * b.w;
}

// ---------- K1: foldv, one row per 192-thr block (2305) | clear deg (22) ----
// v[k] = row_k(Wcat2) . clf_w ; v[2304] = b2.clf_w + clf_b
__global__ __launch_bounds__(192) void foldv_clear_kernel(
    const float* __restrict__ w_root2, const float* __restrict__ w_rel2,
    const float* __restrict__ b2, const float* __restrict__ clf_w,
    const float* __restrict__ clf_b, float* __restrict__ v,
    int* __restrict__ deg) {
  __shared__ float sred[3];
  int b = blockIdx.x;
  int t = threadIdx.x;
  if (b < NROWS) {
    int k = b;
    const float* row = (k < DIM) ? w_root2 + (size_t)k * DIM
                     : (k < 3 * DIM) ? w_rel2 + (size_t)(k - DIM) * DIM
                                     : b2;
    float s = dot4(((const float4*)row)[t], ((const float4*)clf_w)[t]);
    s = wred(s);
    int lane = t & 63, wv = t >> 6;
    if (lane == 0) sred[wv] = s;
    __syncthreads();
    if (t == 0)
      v[k] = sred[0] + sred[1] + sred[2] + (k == 3 * DIM ? clf_b[0] : 0.f);
  } else {
    int i = (b - NROWS) * 192 + t;
    if (i < NBINS) deg[i] = 0;
  }
}

// ---------- K2: bucket-scatter (171, guarded) | foldu row/block (2305) ------
// bucket[bin*CAP + slot] = src, deg[bin] = count  (hist+scatter in one pass)
// U4[k] = {row_k(Wcat1).v0, .v1, .v2}; U4[2304] = d (bias fold)
__global__ __launch_bounds__(192) void bucket_foldu_kernel(
    const int* __restrict__ srcv, const int* __restrict__ dst,
    const int* __restrict__ et, int* __restrict__ deg, int* __restrict__ bucket,
    const float* __restrict__ w_root1, const float* __restrict__ w_rel1,
    const float* __restrict__ b1, const float* __restrict__ v,
    float4* __restrict__ U4) {
  __shared__ float sred[3][3];
  int b = blockIdx.x;
  int t = threadIdx.x;
  if (b < SCATB) {
    int e = b * 192 + t;
    if (e < NEDGES) {
      int bin = et[e] * NNODES + dst[e];
      int slot = atomicAdd(&deg[bin], 1);
      if (slot < CAP) bucket[bin * CAP + slot] = srcv[e];
    }
  } else {
    int k = b - SCATB;
    const float* row = (k < DIM) ? w_root1 + (size_t)k * DIM
                     : (k < 3 * DIM) ? w_rel1 + (size_t)(k - DIM) * DIM
                                     : b1;
    float4 r = ((const float4*)row)[t];
    float s0 = dot4(r, ((const float4*)v)[t]);
    float s1 = dot4(r, ((const float4*)(v + DIM))[t]);
    float s2 = dot4(r, ((const float4*)(v + 2 * DIM))[t]);
    s0 = wred(s0); s1 = wred(s1); s2 = wred(s2);
    int lane = t & 63, wv = t >> 6;
    if (lane == 0) { sred[wv][0] = s0; sred[wv][1] = s1; sred[wv][2] = s2; }
    __syncthreads();
    if (t == 0)
      U4[k] = make_float4(sred[0][0] + sred[1][0] + sred[2][0],
                          sred[0][1] + sred[1][1] + sred[2][1],
                          sred[0][2] + sred[1][2] + sred[2][2], 0.f);
  }
}

// ---------- K3: T[m][a][j] = x0[m].U_a[:,j], one 256-thr block per node ------
// m in [0,1088]; m==1088 is the shared span prototype (token SPAN_TOK).
// Threads 0..191 each own one float4 (4 k's) of the 768-dim; 4-wave LDS reduce.
__global__ __launch_bounds__(256) void t_kernel(
    const int* __restrict__ doc_ids, const int* __restrict__ pass_ids,
    const float* __restrict__ embed, const float4* __restrict__ U4,
    float4* __restrict__ Tq) {
  __shared__ float sred[4][9];
  int m = blockIdx.x;  // 0..1088
  int t = threadIdx.x;
  int wv = t >> 6, lane = t & 63;
  int tok = (m < NDOCS) ? doc_ids[m * TITLE_LEN]
          : (m < NDOCS + NPASS) ? pass_ids[(m - NDOCS) * SEQ]
                                : SPAN_TOK;
  float s[9] = {};
  if (t < 192) {
    const float4* e4 = (const float4*)(embed + (size_t)tok * DIM);
    float4 ev = e4[t];
#pragma unroll
    for (int q = 0; q < 4; ++q) {
      int k = t * 4 + q;
      float e1 = (q == 0) ? ev.x : (q == 1) ? ev.y : (q == 2) ? ev.z : ev.w;
      float4 u0 = U4[k], u1 = U4[DIM + k], u2 = U4[2 * DIM + k];
      s[0] += e1 * u0.x; s[1] += e1 * u0.y; s[2] += e1 * u0.z;
      s[3] += e1 * u1.x; s[4] += e1 * u1.y; s[5] += e1 * u1.z;
      s[6] += e1 * u2.x; s[7] += e1 * u2.y; s[8] += e1 * u2.z;
    }
  }
#pragma unroll
  for (int a = 0; a < 9; ++a) s[a] = wred(s[a]);
  if (lane == 0) {
#pragma unroll
    for (int a = 0; a < 9; ++a) sred[wv][a] = s[a];
  }
  __syncthreads();
  if (t == 0) {
    float r[9];
#pragma unroll
    for (int a = 0; a < 9; ++a)
      r[a] = sred[0][a] + sred[1][a] + sred[2][a] + sred[3][a];
    Tq[m * 4 + 0] = make_float4(r[0], r[1], r[2], 0.f);
    Tq[m * 4 + 1] = make_float4(r[3], r[4], r[5], 0.f);
    Tq[m * 4 + 2] = make_float4(r[6], r[7], r[8], 0.f);
  }
}

// ---------- K4: final, flattened traversal; one 128-thr block per span node --
// z = T[n][0][0] + D[0] + c0 + sum_{own edges (s,r)} i_r(n) * (
//       T[s][1+r][0] + T[s][0][1+r] + D[1+r]
//     + sum_{rp} mean_{s' in bin(rp,s)} T[s'][1+rp][1+r] )
// 4 lanes per outer edge (o = t>>2, stride 32); q-lanes stride-4 over inner
// bins; division by max(cs,1) distributes the mean; 2-wave LDS reduce.
__global__ __launch_bounds__(128) void final_kernel(
    const float4* __restrict__ Tq, const int* __restrict__ deg,
    const int* __restrict__ bucket, const float4* __restrict__ U4,
    const float* __restrict__ v, float* __restrict__ out) {
  __shared__ float red2[2];
  int i = blockIdx.x;  // span idx 0..1023
  int t = threadIdx.x;
  int lane = t & 63, wv = t >> 6;
  int n = SPAN0 + i;
  const float* Tqf = (const float*)Tq;
  float4 D = U4[3 * DIM];
  const float* Df = (const float*)&D;
  int c0n = deg[n], c1n = deg[NNODES + n];
  float i0n = 1.f / fmaxf((float)c0n, 1.f);
  float i1n = 1.f / fmaxf((float)c1n, 1.f);
  int tot = c0n + c1n;
  int q = t & 3;
  float zpart = 0.f;
  for (int o = t >> 2; o < tot; o += 32) {
    int r = (o < c0n) ? 0 : 1;
    int oo = (o < c0n) ? o : o - c0n;
    int s = bucket[(r * NNODES + n) * CAP + oo];
    int j = 1 + r;
    int ts = (s < SPAN0) ? s : SPAN0;
    float contrib = 0.f;
    if (q == 0)
      contrib = Tqf[ts * 16 + j * 4 + 0]  // T[s][1+r][0]
              + Tqf[ts * 16 + j]          // T[s][0][1+r]
              + Df[j];
#pragma unroll
    for (int rp = 0; rp < 2; ++rp) {
      int cs = deg[rp * NNODES + s];
      float ssum = 0.f;
      for (int e = q; e < cs; e += 4) {
        int sp = bucket[(rp * NNODES + s) * CAP + e];
        int tsp = (sp < SPAN0) ? sp : SPAN0;
        ssum += Tqf[tsp * 16 + (1 + rp) * 4 + j];
      }
      contrib += ssum / fmaxf((float)cs, 1.f);
    }
    zpart += ((r == 0) ? i0n : i1n) * contrib;
  }
  zpart = wred(zpart);
  if (lane == 0) red2[wv] = zpart;
  __syncthreads();
  if (t == 0) {
    float z = Tqf[SPAN0 * 16 + 0] + Df[0] + v[3 * DIM] + red2[0] + red2[1];
    float sc = 1.f / (1.f + expf(-z));
    out[i] = expf(sc * 5.f);  // exp(score / TAU), TAU = 0.2
  }
}

extern "C" void kernel_launch(void* const* d_in, const int* in_sizes, int n_in,
                              void* d_out, int out_size, void* d_ws, size_t ws_size,
                              hipStream_t stream) {
  const int* doc_ids = (const int*)d_in[0];
  const int* pass_ids = (const int*)d_in[1];
  const int* edge_index = (const int*)d_in[2];
  const int* etype = (const int*)d_in[3];
  const float* embed = (const float*)d_in[4];
  const float* w_root1 = (const float*)d_in[5];
  const float* w_rel1 = (const float*)d_in[6];
  const float* b1 = (const float*)d_in[7];
  const float* w_root2 = (const float*)d_in[8];
  const float* w_rel2 = (const float*)d_in[9];
  const float* b2 = (const float*)d_in[10];
  const float* clf_w = (const float*)d_in[11];
  const float* clf_b = (const float*)d_in[12];
  float* out = (float*)d_out;

  const int* src = edge_index;
  const int* dst = edge_index + NEDGES;

  float4* U4 = (float4*)d_ws;                      // 2305 float4
  float4* Tq = U4 + NROWS;                         // 1089*4 float4
  float* v = (float*)(Tq + (size_t)(SPAN0 + 1) * 4);  // 2305 floats
  int* deg = (int*)(v + NROWS);                    // NBINS
  int* bucket = deg + NBINS;                       // NBINS * CAP

  foldv_clear_kernel<<<NROWS + 22, 192, 0, stream>>>(w_root2, w_rel2, b2, clf_w,
                                                     clf_b, v, deg);
  bucket_foldu_kernel<<<SCATB + NROWS, 192, 0, stream>>>(src, dst, etype, deg,
                                                         bucket, w_root1,
                                                         w_rel1, b1, v, U4);
  t_kernel<<<SPAN0 + 1, 256, 0, stream>>>(doc_ids, pass_ids, embed, U4, Tq);
  final_kernel<<<NPASS, 128, 0, stream>>>(Tq, deg, bucket, U4, v, out);
}